// Round 2
// baseline (223.465 us; speedup 1.0000x reference)
//
#include <hip/hip_runtime.h>

// Problem constants
#define Bn  16
#define Ln  224
#define K1n 8192
#define Pn  16

// ---------------------------------------------------------------------------
// Kernel 1: per-(b,k) compute h3[p] and reduce sum/max over k; capture mid.
// Grid: 512 blocks (32 per b), 256 threads, one k per thread.
// ---------------------------------------------------------------------------
__global__ __launch_bounds__(256) void k_stats(
    const float* __restrict__ y,      // [B, L, K1] f32
    const float* __restrict__ w3c,    // [1, L, P]  f32
    const float* __restrict__ sigma,  // [1]        f32
    float* __restrict__ ws_sum,       // [B*P]  (zeroed)
    unsigned int* __restrict__ ws_max,// [B*P]  (zeroed; h3>0 so uint-max works)
    float* __restrict__ ws_mid)       // [B*P]
{
    __shared__ float s_w3c[Ln][Pn];   // 14 KiB
    __shared__ float s_csq[Pn];
    __shared__ float s_part_s[4][Pn];
    __shared__ float s_part_m[4][Pn];

    const int tid = threadIdx.x;
    const int b   = blockIdx.x >> 5;               // 32 blocks per batch
    const int k   = ((blockIdx.x & 31) << 8) + tid;

    // Stage w3_c into LDS
    for (int i = tid; i < Ln * Pn; i += 256) {
        s_w3c[i >> 4][i & 15] = w3c[i];
    }
    __syncthreads();
    if (tid < Pn) {
        float cs = 0.f;
        for (int l = 0; l < Ln; ++l) { float v = s_w3c[l][tid]; cs = fmaf(v, v, cs); }
        s_csq[tid] = cs;
    }
    __syncthreads();

    // Main loop over L: y_sq and cross[p]
    float cross[Pn];
#pragma unroll
    for (int p = 0; p < Pn; ++p) cross[p] = 0.f;
    float ysq = 0.f;

    const float* yp = y + (size_t)b * Ln * K1n + k;
#pragma unroll 8
    for (int l = 0; l < Ln; ++l) {
        float v = yp[(size_t)l * K1n];
        ysq = fmaf(v, v, ysq);
#pragma unroll
        for (int p = 0; p < Pn; ++p) cross[p] = fmaf(v, s_w3c[l][p], cross[p]);
    }

    const float sg = sigma[0];
    const float neg_half_inv_s2 = -0.5f / (sg * sg);

    float h3[Pn];
#pragma unroll
    for (int p = 0; p < Pn; ++p) {
        float d = ysq + s_csq[p] - 2.f * cross[p];
        d = fmaxf(d, 0.f);
        h3[p] = __expf(d * neg_half_inv_s2);
    }

    // mid = h3[b, p, K1/2]
    if (k == (K1n / 2)) {
#pragma unroll
        for (int p = 0; p < Pn; ++p) ws_mid[b * Pn + p] = h3[p];
    }

    // Wave-level reduce (sum & max) per p, then cross-wave via LDS + atomics
    const int lane = tid & 63;
    const int wv   = tid >> 6;
#pragma unroll
    for (int p = 0; p < Pn; ++p) {
        float s = h3[p];
        float m = h3[p];
#pragma unroll
        for (int off = 32; off > 0; off >>= 1) {
            s += __shfl_down(s, off, 64);
            m = fmaxf(m, __shfl_down(m, off, 64));
        }
        if (lane == 0) { s_part_s[wv][p] = s; s_part_m[wv][p] = m; }
    }
    __syncthreads();
    if (tid < Pn) {
        float s = s_part_s[0][tid] + s_part_s[1][tid] + s_part_s[2][tid] + s_part_s[3][tid];
        float m = fmaxf(fmaxf(s_part_m[0][tid], s_part_m[1][tid]),
                        fmaxf(s_part_m[2][tid], s_part_m[3][tid]));
        atomicAdd(&ws_sum[b * Pn + tid], s);
        atomicMax(&ws_max[b * Pn + tid], __float_as_uint(m));
    }
}

// ---------------------------------------------------------------------------
// Kernel 2: per-block tiny finalize (h4[b,p]) + out = h4 + w3_w@(a-d2).
// Grid: 512 blocks (32 per b), 256 threads, one k per thread.
// ---------------------------------------------------------------------------
__global__ __launch_bounds__(256) void k_out(
    const float* __restrict__ a,      // [B, P, K1] f32
    const float* __restrict__ d2,     // [B, P, K1] f32
    const float* __restrict__ w3w,    // [P, P] f32
    const float* __restrict__ b3w,    // [P, P] f32
    const float* __restrict__ caw,    // [2, P] f32
    const float* __restrict__ ws_sum,
    const unsigned int* __restrict__ ws_max,
    const float* __restrict__ ws_mid,
    float* __restrict__ out)          // [B, P, K1] f32
{
    __shared__ float s_w3w[Pn][Pn];
    __shared__ float s_avg[Pn], s_mx[Pn], s_mid[Pn], s_comb[Pn], s_h4[Pn];
    __shared__ float s_t[2];

    const int tid = threadIdx.x;
    const int b   = blockIdx.x >> 5;
    const int k   = ((blockIdx.x & 31) << 8) + tid;

    if (tid < Pn * Pn) s_w3w[tid >> 4][tid & 15] = w3w[tid];
    if (tid < Pn) {
        s_avg[tid] = ws_sum[b * Pn + tid] * (1.f / (float)K1n);
        s_mx[tid]  = __uint_as_float(ws_max[b * Pn + tid]);
        s_mid[tid] = ws_mid[b * Pn + tid];
    }
    __syncthreads();

    if (tid < 2) {
        float t1 = 0.f, t2 = 0.f;
        for (int p = 0; p < Pn; ++p) {
            float cw = caw[tid * Pn + p];
            t1 = fmaf(cw, s_avg[p], t1);
            t2 = fmaf(cw, s_mx[p],  t2);
        }
        t1 = (t1 > 0.f) ? t1 : 0.01f * t1;   // leaky_relu
        t2 = (t2 > 0.f) ? t2 : 0.01f * t2;
        s_t[tid] = t1 + t2;
    }
    __syncthreads();

    if (tid < Pn) {
        // softmax over the 2 logits (redundant per thread, trivial)
        float t0 = s_t[0], u1 = s_t[1];
        float mt = fmaxf(t0, u1);
        float e0 = __expf(t0 - mt), e1 = __expf(u1 - mt);
        float inv = 1.f / (e0 + e1);
        s_comb[tid] = (e0 * inv) * s_mid[tid] + (e1 * inv) * s_avg[tid];
    }
    __syncthreads();

    if (tid < Pn) {
        float h = 0.f;
        for (int q = 0; q < Pn; ++q) h = fmaf(b3w[tid * Pn + q], s_comb[q], h);
        s_h4[tid] = h;
    }
    __syncthreads();

    // Main: diff[q] = (a - d2)[b, q, k]; out[b, p, k] = h4[p] + w3_w[p,:]·diff
    const size_t base = (size_t)b * Pn * K1n + (size_t)k;
    float diff[Pn];
#pragma unroll
    for (int q = 0; q < Pn; ++q) {
        float av = a [base + (size_t)q * K1n];
        float dv = d2[base + (size_t)q * K1n];
        diff[q] = av - dv;
    }
#pragma unroll
    for (int p = 0; p < Pn; ++p) {
        float h2 = 0.f;
#pragma unroll
        for (int q = 0; q < Pn; ++q) h2 = fmaf(s_w3w[p][q], diff[q], h2);
        out[base + (size_t)p * K1n] = h2 + s_h4[p];
    }
}

// ---------------------------------------------------------------------------
extern "C" void kernel_launch(void* const* d_in, const int* in_sizes, int n_in,
                              void* d_out, int out_size, void* d_ws, size_t ws_size,
                              hipStream_t stream) {
    const float* a     = (const float*)d_in[0];
    const float* d2    = (const float*)d_in[1];
    const float* y     = (const float*)d_in[2];
    const float* w3w   = (const float*)d_in[3];
    const float* b3w   = (const float*)d_in[4];
    const float* w3c   = (const float*)d_in[5];
    const float* sigma = (const float*)d_in[6];
    const float* caw   = (const float*)d_in[7];

    float*        ws_sum = (float*)d_ws;
    unsigned int* ws_max = (unsigned int*)((char*)d_ws + Bn * Pn * sizeof(float));
    float*        ws_mid = (float*)((char*)d_ws + 2 * Bn * Pn * sizeof(float));

    // Zero the accumulators (ws is poisoned 0xAA before every launch)
    hipMemsetAsync(d_ws, 0, 3 * Bn * Pn * sizeof(float), stream);

    k_stats<<<dim3(Bn * (K1n / 256)), dim3(256), 0, stream>>>(
        y, w3c, sigma, ws_sum, ws_max, ws_mid);

    k_out<<<dim3(Bn * (K1n / 256)), dim3(256), 0, stream>>>(
        a, d2, w3w, b3w, caw, ws_sum, ws_max, ws_mid, (float*)d_out);
}

// Round 3
// 215.604 us; speedup vs baseline: 1.0365x; 1.0365x over previous
//
#include <hip/hip_runtime.h>

// Problem constants
#define Bn  16
#define Ln  224
#define K1n 8192
#define Pn  16
#define NCHUNK 32   // k-chunks per batch (blocks per b in k_stats)

// ws layout (floats):
//   ws_sum : [Bn][NCHUNK][Pn]   per-block partial sums   (16*32*16 = 8192)
//   ws_max : [Bn][NCHUNK][Pn]   per-block partial maxes  (8192)
//   ws_mid : [Bn][Pn]           h3 at k = K1/2           (256)
// Every slot is unconditionally written by exactly one block -> no zeroing,
// no atomics, safe under the harness's 0xAA ws poison.

// ---------------------------------------------------------------------------
// Kernel 1: per-(b,k) compute h3[p]; per-block reduce sum/max over its 256 k.
// Grid: 512 blocks (32 per b), 256 threads, one k per thread.
// ---------------------------------------------------------------------------
__global__ __launch_bounds__(256) void k_stats(
    const float* __restrict__ y,      // [B, L, K1] f32
    const float* __restrict__ w3c,    // [1, L, P]  f32
    const float* __restrict__ sigma,  // [1]        f32
    float* __restrict__ ws_sum,
    float* __restrict__ ws_max,
    float* __restrict__ ws_mid)
{
    __shared__ float s_w3c[Ln][Pn];   // 14 KiB
    __shared__ float s_csq[Pn];
    __shared__ float s_part_s[4][Pn];
    __shared__ float s_part_m[4][Pn];

    const int tid   = threadIdx.x;
    const int b     = blockIdx.x >> 5;         // 32 blocks per batch
    const int chunk = blockIdx.x & 31;
    const int k     = (chunk << 8) + tid;

    // Stage w3_c into LDS
    for (int i = tid; i < Ln * Pn; i += 256) {
        s_w3c[i >> 4][i & 15] = w3c[i];
    }
    __syncthreads();
    if (tid < Pn) {
        float cs = 0.f;
        for (int l = 0; l < Ln; ++l) { float v = s_w3c[l][tid]; cs = fmaf(v, v, cs); }
        s_csq[tid] = cs;
    }
    __syncthreads();

    // Main loop over L: y_sq and cross[p]
    float cross[Pn];
#pragma unroll
    for (int p = 0; p < Pn; ++p) cross[p] = 0.f;
    float ysq = 0.f;

    const float* yp = y + (size_t)b * Ln * K1n + k;
#pragma unroll 16
    for (int l = 0; l < Ln; ++l) {
        float v = yp[(size_t)l * K1n];
        ysq = fmaf(v, v, ysq);
#pragma unroll
        for (int p = 0; p < Pn; ++p) cross[p] = fmaf(v, s_w3c[l][p], cross[p]);
    }

    const float sg = sigma[0];
    const float neg_half_inv_s2 = -0.5f / (sg * sg);

    float h3[Pn];
#pragma unroll
    for (int p = 0; p < Pn; ++p) {
        float d = ysq + s_csq[p] - 2.f * cross[p];
        d = fmaxf(d, 0.f);
        h3[p] = __expf(d * neg_half_inv_s2);
    }

    // mid = h3[b, p, K1/2] : k == 4096 -> chunk == 16, tid == 0
    if (k == (K1n / 2)) {
#pragma unroll
        for (int p = 0; p < Pn; ++p) ws_mid[b * Pn + p] = h3[p];
    }

    // Wave-level reduce (sum & max) per p, then cross-wave via LDS
    const int lane = tid & 63;
    const int wv   = tid >> 6;
#pragma unroll
    for (int p = 0; p < Pn; ++p) {
        float s = h3[p];
        float m = h3[p];
#pragma unroll
        for (int off = 32; off > 0; off >>= 1) {
            s += __shfl_down(s, off, 64);
            m = fmaxf(m, __shfl_down(m, off, 64));
        }
        if (lane == 0) { s_part_s[wv][p] = s; s_part_m[wv][p] = m; }
    }
    __syncthreads();
    if (tid < Pn) {
        float s = s_part_s[0][tid] + s_part_s[1][tid] + s_part_s[2][tid] + s_part_s[3][tid];
        float m = fmaxf(fmaxf(s_part_m[0][tid], s_part_m[1][tid]),
                        fmaxf(s_part_m[2][tid], s_part_m[3][tid]));
        const int base = (b * NCHUNK + chunk) * Pn + tid;
        ws_sum[base] = s;
        ws_max[base] = m;
    }
}

// ---------------------------------------------------------------------------
// Kernel 2: reduce partials + tiny finalize (h4[b,p]) + out = h4 + w3_w@(a-d2).
// Grid: 512 blocks (32 per b), 256 threads, one k per thread.
// ---------------------------------------------------------------------------
__global__ __launch_bounds__(256) void k_out(
    const float* __restrict__ a,      // [B, P, K1] f32
    const float* __restrict__ d2,     // [B, P, K1] f32
    const float* __restrict__ w3w,    // [P, P] f32
    const float* __restrict__ b3w,    // [P, P] f32
    const float* __restrict__ caw,    // [2, P] f32
    const float* __restrict__ ws_sum,
    const float* __restrict__ ws_max,
    const float* __restrict__ ws_mid,
    float* __restrict__ out)          // [B, P, K1] f32
{
    __shared__ float s_w3w[Pn][Pn];
    __shared__ float s_red_s[16][Pn];   // 16 groups x 16 p
    __shared__ float s_red_m[16][Pn];
    __shared__ float s_avg[Pn], s_mx[Pn], s_mid[Pn], s_comb[Pn], s_h4[Pn];
    __shared__ float s_t[2];

    const int tid = threadIdx.x;
    const int b   = blockIdx.x >> 5;
    const int k   = ((blockIdx.x & 31) << 8) + tid;

    if (tid < Pn * Pn) s_w3w[tid >> 4][tid & 15] = w3w[tid];

    // Parallel partial-reduce: thread (grp, p) handles chunks grp and grp+16
    {
        const int p   = tid & 15;
        const int grp = tid >> 4;          // 0..15
        const int i0  = (b * NCHUNK + grp)      * Pn + p;
        const int i1  = (b * NCHUNK + grp + 16) * Pn + p;
        s_red_s[grp][p] = ws_sum[i0] + ws_sum[i1];
        s_red_m[grp][p] = fmaxf(ws_max[i0], ws_max[i1]);
    }
    __syncthreads();
    if (tid < Pn) {
        float s = 0.f, m = -1.f;
        for (int g = 0; g < 16; ++g) {
            s += s_red_s[g][tid];
            m = fmaxf(m, s_red_m[g][tid]);
        }
        s_avg[tid] = s * (1.f / (float)K1n);
        s_mx[tid]  = m;
        s_mid[tid] = ws_mid[b * Pn + tid];
    }
    __syncthreads();

    if (tid < 2) {
        float t1 = 0.f, t2 = 0.f;
        for (int p = 0; p < Pn; ++p) {
            float cw = caw[tid * Pn + p];
            t1 = fmaf(cw, s_avg[p], t1);
            t2 = fmaf(cw, s_mx[p],  t2);
        }
        t1 = (t1 > 0.f) ? t1 : 0.01f * t1;   // leaky_relu
        t2 = (t2 > 0.f) ? t2 : 0.01f * t2;
        s_t[tid] = t1 + t2;
    }
    __syncthreads();

    if (tid < Pn) {
        // softmax over the 2 logits (redundant per thread, trivial)
        float t0 = s_t[0], u1 = s_t[1];
        float mt = fmaxf(t0, u1);
        float e0 = __expf(t0 - mt), e1 = __expf(u1 - mt);
        float inv = 1.f / (e0 + e1);
        s_comb[tid] = (e0 * inv) * s_mid[tid] + (e1 * inv) * s_avg[tid];
    }
    __syncthreads();

    if (tid < Pn) {
        float h = 0.f;
        for (int q = 0; q < Pn; ++q) h = fmaf(b3w[tid * Pn + q], s_comb[q], h);
        s_h4[tid] = h;
    }
    __syncthreads();

    // Main: diff[q] = (a - d2)[b, q, k]; out[b, p, k] = h4[p] + w3_w[p,:]·diff
    const size_t base = (size_t)b * Pn * K1n + (size_t)k;
    float diff[Pn];
#pragma unroll
    for (int q = 0; q < Pn; ++q) {
        float av = a [base + (size_t)q * K1n];
        float dv = d2[base + (size_t)q * K1n];
        diff[q] = av - dv;
    }
#pragma unroll
    for (int p = 0; p < Pn; ++p) {
        float h2 = 0.f;
#pragma unroll
        for (int q = 0; q < Pn; ++q) h2 = fmaf(s_w3w[p][q], diff[q], h2);
        out[base + (size_t)p * K1n] = h2 + s_h4[p];
    }
}

// ---------------------------------------------------------------------------
extern "C" void kernel_launch(void* const* d_in, const int* in_sizes, int n_in,
                              void* d_out, int out_size, void* d_ws, size_t ws_size,
                              hipStream_t stream) {
    const float* a     = (const float*)d_in[0];
    const float* d2    = (const float*)d_in[1];
    const float* y     = (const float*)d_in[2];
    const float* w3w   = (const float*)d_in[3];
    const float* b3w   = (const float*)d_in[4];
    const float* w3c   = (const float*)d_in[5];
    const float* sigma = (const float*)d_in[6];
    const float* caw   = (const float*)d_in[7];

    float* ws_sum = (float*)d_ws;
    float* ws_max = ws_sum + Bn * NCHUNK * Pn;
    float* ws_mid = ws_max + Bn * NCHUNK * Pn;

    k_stats<<<dim3(Bn * NCHUNK), dim3(256), 0, stream>>>(
        y, w3c, sigma, ws_sum, ws_max, ws_mid);

    k_out<<<dim3(Bn * NCHUNK), dim3(256), 0, stream>>>(
        a, d2, w3w, b3w, caw, ws_sum, ws_max, ws_mid, (float*)d_out);
}